// Round 1
// baseline (550.762 us; speedup 1.0000x reference)
//
#include <hip/hip_runtime.h>

// ---------------------------------------------------------------------------
// GCN 2-layer forward on MI355X.
// out = relu(Ahat * relu((Ahat*X)*W1 + b1) * W2 + b2),  Ahat = D^-1/2 (A+I) D^-1/2
// Aggregation done on the 128-wide side of each layer (associativity).
// CSR (by dst) rebuilt every call (ws is re-poisoned); pull-based agg, no fp atomics.
// ---------------------------------------------------------------------------

#define C_IN   128
#define C_HID  256
#define C_OUT  128

// ---------------- degree histogram ----------------
__global__ void deg_kernel(const int* __restrict__ dst, int* __restrict__ counts, int E) {
    int e = blockIdx.x * blockDim.x + threadIdx.x;
    if (e < E) atomicAdd(&counts[dst[e]], 1);
}

__global__ void dinv_kernel(const int* __restrict__ counts, float* __restrict__ dinv, int n) {
    int i = blockIdx.x * blockDim.x + threadIdx.x;
    if (i < n) dinv[i] = rsqrtf((float)(counts[i] + 1));   // +1 self-loop
}

// ---------------- single-block scan (n=50000, 1024 threads) ----------------
#define SCAN_T 1024
__global__ __launch_bounds__(SCAN_T) void scan_kernel(const int* __restrict__ counts,
                                                      int* __restrict__ offsets,
                                                      int* __restrict__ cursor, int n) {
    __shared__ int partial[SCAN_T];
    int t = threadIdx.x;
    int chunk = (n + SCAN_T - 1) / SCAN_T;
    int lo = t * chunk;
    int hi = min(lo + chunk, n);
    int s = 0;
    for (int i = lo; i < hi; ++i) s += counts[i];
    partial[t] = s;
    __syncthreads();
    for (int off = 1; off < SCAN_T; off <<= 1) {
        int v = (t >= off) ? partial[t - off] : 0;
        __syncthreads();
        partial[t] += v;
        __syncthreads();
    }
    int run = (t == 0) ? 0 : partial[t - 1];   // exclusive prefix of this chunk
    for (int i = lo; i < hi; ++i) {
        int c = counts[i];
        offsets[i] = run;
        cursor[i]  = run;
        run += c;
    }
    if (t == SCAN_T - 1) offsets[n] = run;     // == E
}

__global__ void fill_csr(const int* __restrict__ src, const int* __restrict__ dst,
                         int* __restrict__ cursor, int* __restrict__ csr_src, int E) {
    int e = blockIdx.x * blockDim.x + threadIdx.x;
    if (e < E) {
        int p = atomicAdd(&cursor[dst[e]], 1);
        csr_src[p] = src[e];
    }
}

// ---------------- pull aggregation, 128-wide ----------------
// out[i][c] = dinv[i] * ( dinv[i]*h[i][c] + sum_{j in N(i)} dinv[j]*h[j][c] ) (+bias)(relu)
__global__ __launch_bounds__(128) void agg128_kernel(
        const float* __restrict__ h, const int* __restrict__ offsets,
        const int* __restrict__ csr_src, const float* __restrict__ dinv,
        const float* __restrict__ bias, float* __restrict__ out,
        int relu_flag, int n) {
    int i = blockIdx.x;
    int c = threadIdx.x;            // 0..127
    float di = dinv[i];
    float acc = di * h[(size_t)i * 128 + c];     // self-loop term (x di again at end)
    int lo = offsets[i], hi = offsets[i + 1];
    for (int k = lo; k < hi; ++k) {
        int j = csr_src[k];                      // wave-uniform -> scalarized
        acc += dinv[j] * h[(size_t)j * 128 + c];
    }
    float v = di * acc;
    if (bias) v += bias[c];
    if (relu_flag) v = fmaxf(v, 0.0f);
    out[(size_t)i * 128 + c] = v;
}

// ---------------- fp32 SGEMM, fused bias+relu epilogue ----------------
// C[MxN] = A[MxK] * B[KxN]; BM=BN=64, BK=16, 256 threads, 4x4 per thread.
#define BM 64
#define BN 64
#define BK 16
__global__ __launch_bounds__(256) void sgemm_bias_relu(
        const float* __restrict__ A, const float* __restrict__ B,
        const float* __restrict__ bias, float* __restrict__ C,
        int M, int K, int N, int relu_flag) {
    __shared__ float As[BK][68];   // A tile transposed [k][row], padded (68: 16B-aligned rows, no hot conflicts)
    __shared__ float Bs[BK][BN];

    int tid = threadIdx.x;
    int tx = tid & 15;             // 0..15 (N dir)
    int ty = tid >> 4;             // 0..15 (M dir)
    int row0 = blockIdx.x * BM;
    int col0 = blockIdx.y * BN;

    // A-load mapping: one float4 per thread, tile 64 rows x 16 cols
    int a_r  = tid >> 2;           // 0..63
    int a_c4 = tid & 3;            // 0..3
    int a_row = row0 + a_r;
    bool a_ok = a_row < M;
    // B-load mapping: one float4 per thread, tile 16 rows x 64 cols
    int b_r  = tid >> 4;           // 0..15
    int b_c4 = tid & 15;           // 0..15

    float acc[4][4] = {};

    for (int k0 = 0; k0 < K; k0 += BK) {
        float4 av = a_ok ? *(const float4*)(A + (size_t)a_row * K + k0 + a_c4 * 4)
                         : make_float4(0.f, 0.f, 0.f, 0.f);
        float4 bv = *(const float4*)(B + (size_t)(k0 + b_r) * N + col0 + b_c4 * 4);
        __syncthreads();           // previous iter done reading LDS
        As[a_c4 * 4 + 0][a_r] = av.x;
        As[a_c4 * 4 + 1][a_r] = av.y;
        As[a_c4 * 4 + 2][a_r] = av.z;
        As[a_c4 * 4 + 3][a_r] = av.w;
        *(float4*)(&Bs[b_r][b_c4 * 4]) = bv;
        __syncthreads();
        #pragma unroll
        for (int k = 0; k < BK; ++k) {
            float4 a4 = *(const float4*)(&As[k][ty * 4]);
            float4 b4 = *(const float4*)(&Bs[k][tx * 4]);
            float ar[4] = {a4.x, a4.y, a4.z, a4.w};
            float br[4] = {b4.x, b4.y, b4.z, b4.w};
            #pragma unroll
            for (int i = 0; i < 4; ++i)
                #pragma unroll
                for (int j = 0; j < 4; ++j)
                    acc[i][j] += ar[i] * br[j];
        }
    }

    #pragma unroll
    for (int i = 0; i < 4; ++i) {
        int r = row0 + ty * 4 + i;
        if (r < M) {
            float4 v;
            float* vp = &v.x;
            #pragma unroll
            for (int j = 0; j < 4; ++j) {
                float x = acc[i][j];
                if (bias) x += bias[col0 + tx * 4 + j];
                if (relu_flag) x = fmaxf(x, 0.0f);
                vp[j] = x;
            }
            *(float4*)(C + (size_t)r * N + col0 + tx * 4) = v;
        }
    }
}

// ---------------------------------------------------------------------------
extern "C" void kernel_launch(void* const* d_in, const int* in_sizes, int n_in,
                              void* d_out, int out_size, void* d_ws, size_t ws_size,
                              hipStream_t stream) {
    const float* x  = (const float*)d_in[0];
    const int*   ei = (const int*)d_in[1];
    const float* W1 = (const float*)d_in[2];
    const float* b1 = (const float*)d_in[3];
    const float* W2 = (const float*)d_in[4];
    const float* b2 = (const float*)d_in[5];

    const int n = in_sizes[0] / C_IN;          // 50000
    const int E = in_sizes[1] / 2;             // 800000

    const int* src = ei;
    const int* dst = ei + E;

    // workspace layout (~81 MB)
    float* z1   = (float*)d_ws;                          // n*256
    float* h2   = z1 + (size_t)n * C_HID;                // n*128
    float* dinv = h2 + (size_t)n * C_OUT;                // n
    int* counts  = (int*)(dinv + n);                     // n
    int* offsets = counts + n;                           // n+1
    int* cursor  = offsets + (n + 1);                    // n
    int* csr_src = cursor + n;                           // E

    float* agg0 = (float*)d_out;   // scratch for Ahat*X (overwritten by final write)
    float* outp = (float*)d_out;

    // ---- CSR build ----
    hipMemsetAsync(counts, 0, (size_t)n * sizeof(int), stream);
    deg_kernel<<<(E + 255) / 256, 256, 0, stream>>>(dst, counts, E);
    dinv_kernel<<<(n + 255) / 256, 256, 0, stream>>>(counts, dinv, n);
    scan_kernel<<<1, SCAN_T, 0, stream>>>(counts, offsets, cursor, n);
    fill_csr<<<(E + 255) / 256, 256, 0, stream>>>(src, dst, cursor, csr_src, E);

    // ---- layer 1: agg0 = Ahat*X ; z1 = relu(agg0@W1 + b1) ----
    agg128_kernel<<<n, 128, 0, stream>>>(x, offsets, csr_src, dinv,
                                         nullptr, agg0, 0, n);
    {
        dim3 grid((n + BM - 1) / BM, C_HID / BN);
        sgemm_bias_relu<<<grid, 256, 0, stream>>>(agg0, W1, b1, z1, n, C_IN, C_HID, 1);
    }

    // ---- layer 2: h2 = z1@W2 ; out = relu(Ahat*h2 + b2) ----
    {
        dim3 grid((n + BM - 1) / BM, C_OUT / BN);
        sgemm_bias_relu<<<grid, 256, 0, stream>>>(z1, W2, nullptr, h2, n, C_HID, C_OUT, 0);
    }
    agg128_kernel<<<n, 128, 0, stream>>>(h2, offsets, csr_src, dinv,
                                         b2, outp, 1, n);
}

// Round 2
// 458.500 us; speedup vs baseline: 1.2012x; 1.2012x over previous
//
#include <hip/hip_runtime.h>

// ---------------------------------------------------------------------------
// GCN 2-layer forward on MI355X.
// out = relu(Ahat * relu((Ahat*X)*W1 + b1) * W2 + b2),  Ahat = D^-1/2 (A+I) D^-1/2
// Aggregation done on the 128-wide side of each layer (associativity).
// CSR (by dst) rebuilt every call; pull-based agg, no fp atomics.
// R1: replaced single-block scan (110 us, latency-bound on 1 CU) with
//     3-phase multi-block scan (+fused dinv). Everything else unchanged.
// ---------------------------------------------------------------------------

#define C_IN   128
#define C_HID  256
#define C_OUT  128

// ---------------- degree histogram ----------------
__global__ void deg_kernel(const int* __restrict__ dst, int* __restrict__ counts, int E) {
    int e = blockIdx.x * blockDim.x + threadIdx.x;
    if (e < E) atomicAdd(&counts[dst[e]], 1);
}

// ---------------- multi-block scan: 1024 counts per block ----------------
#define SCHUNK 1024

__global__ __launch_bounds__(256) void scan_reduce(const int* __restrict__ counts,
                                                   int* __restrict__ block_sums, int n) {
    int b = blockIdx.x;
    int base = b * SCHUNK;
    int t = threadIdx.x;
    int s = 0;
    #pragma unroll
    for (int u = 0; u < 4; ++u) {
        int i = base + t * 4 + u;
        if (i < n) s += counts[i];
    }
    #pragma unroll
    for (int off = 32; off; off >>= 1) s += __shfl_down(s, off, 64);
    __shared__ int ws[4];
    int wave = t >> 6;
    if ((t & 63) == 0) ws[wave] = s;
    __syncthreads();
    if (t == 0) block_sums[b] = ws[0] + ws[1] + ws[2] + ws[3];
}

// one wave scans the (<=64) block sums
__global__ __launch_bounds__(64) void scan_sums(const int* __restrict__ block_sums,
                                                int* __restrict__ block_base, int nb,
                                                int* __restrict__ offsets, int n, int E) {
    int t = threadIdx.x;
    int v = (t < nb) ? block_sums[t] : 0;
    int x = v;
    #pragma unroll
    for (int off = 1; off < 64; off <<= 1) {
        int y = __shfl_up(x, off, 64);
        if (t >= off) x += y;
    }
    if (t < nb) block_base[t] = x - v;          // exclusive prefix
    if (t == 0) offsets[n] = E;                 // total degree == E by construction
}

// per-block exclusive scan + write offsets/cursor + fused dinv
__global__ __launch_bounds__(256) void scan_apply(const int* __restrict__ counts,
                                                  const int* __restrict__ block_base,
                                                  int* __restrict__ offsets,
                                                  int* __restrict__ cursor,
                                                  float* __restrict__ dinv, int n) {
    int b = blockIdx.x;
    int base_i = b * SCHUNK;
    int t = threadIdx.x;
    int c[4];
    #pragma unroll
    for (int u = 0; u < 4; ++u) {
        int i = base_i + t * 4 + u;
        c[u] = (i < n) ? counts[i] : 0;
    }
    int tot = c[0] + c[1] + c[2] + c[3];
    int x = tot;
    int lane = t & 63;
    #pragma unroll
    for (int off = 1; off < 64; off <<= 1) {
        int y = __shfl_up(x, off, 64);
        if (lane >= off) x += y;
    }
    __shared__ int ws[4];
    int wave = t >> 6;
    if (lane == 63) ws[wave] = x;               // wave total
    __syncthreads();
    int wbase = 0;
    for (int w = 0; w < wave; ++w) wbase += ws[w];
    int run = block_base[b] + wbase + (x - tot);   // exclusive prefix of this thread
    #pragma unroll
    for (int u = 0; u < 4; ++u) {
        int i = base_i + t * 4 + u;
        if (i < n) {
            offsets[i] = run;
            cursor[i]  = run;
            dinv[i]    = rsqrtf((float)(c[u] + 1));   // +1 self-loop
            run += c[u];
        }
    }
}

__global__ void fill_csr(const int* __restrict__ src, const int* __restrict__ dst,
                         int* __restrict__ cursor, int* __restrict__ csr_src, int E) {
    int e = blockIdx.x * blockDim.x + threadIdx.x;
    if (e < E) {
        int p = atomicAdd(&cursor[dst[e]], 1);
        csr_src[p] = src[e];
    }
}

// ---------------- pull aggregation, 128-wide ----------------
// out[i][c] = dinv[i] * ( dinv[i]*h[i][c] + sum_{j in N(i)} dinv[j]*h[j][c] ) (+bias)(relu)
__global__ __launch_bounds__(128) void agg128_kernel(
        const float* __restrict__ h, const int* __restrict__ offsets,
        const int* __restrict__ csr_src, const float* __restrict__ dinv,
        const float* __restrict__ bias, float* __restrict__ out,
        int relu_flag, int n) {
    int i = blockIdx.x;
    int c = threadIdx.x;            // 0..127
    float di = dinv[i];
    float acc = di * h[(size_t)i * 128 + c];     // self-loop term (x di again at end)
    int lo = offsets[i], hi = offsets[i + 1];
    for (int k = lo; k < hi; ++k) {
        int j = csr_src[k];                      // wave-uniform -> scalarized
        acc += dinv[j] * h[(size_t)j * 128 + c];
    }
    float v = di * acc;
    if (bias) v += bias[c];
    if (relu_flag) v = fmaxf(v, 0.0f);
    out[(size_t)i * 128 + c] = v;
}

// ---------------- fp32 SGEMM, fused bias+relu epilogue ----------------
// C[MxN] = A[MxK] * B[KxN]; BM=BN=64, BK=16, 256 threads, 4x4 per thread.
#define BM 64
#define BN 64
#define BK 16
__global__ __launch_bounds__(256) void sgemm_bias_relu(
        const float* __restrict__ A, const float* __restrict__ B,
        const float* __restrict__ bias, float* __restrict__ C,
        int M, int K, int N, int relu_flag) {
    __shared__ float As[BK][68];   // A tile transposed [k][row], padded
    __shared__ float Bs[BK][BN];

    int tid = threadIdx.x;
    int tx = tid & 15;             // 0..15 (N dir)
    int ty = tid >> 4;             // 0..15 (M dir)
    int row0 = blockIdx.x * BM;
    int col0 = blockIdx.y * BN;

    int a_r  = tid >> 2;           // 0..63
    int a_c4 = tid & 3;            // 0..3
    int a_row = row0 + a_r;
    bool a_ok = a_row < M;
    int b_r  = tid >> 4;           // 0..15
    int b_c4 = tid & 15;           // 0..15

    float acc[4][4] = {};

    for (int k0 = 0; k0 < K; k0 += BK) {
        float4 av = a_ok ? *(const float4*)(A + (size_t)a_row * K + k0 + a_c4 * 4)
                         : make_float4(0.f, 0.f, 0.f, 0.f);
        float4 bv = *(const float4*)(B + (size_t)(k0 + b_r) * N + col0 + b_c4 * 4);
        __syncthreads();           // previous iter done reading LDS
        As[a_c4 * 4 + 0][a_r] = av.x;
        As[a_c4 * 4 + 1][a_r] = av.y;
        As[a_c4 * 4 + 2][a_r] = av.z;
        As[a_c4 * 4 + 3][a_r] = av.w;
        *(float4*)(&Bs[b_r][b_c4 * 4]) = bv;
        __syncthreads();
        #pragma unroll
        for (int k = 0; k < BK; ++k) {
            float4 a4 = *(const float4*)(&As[k][ty * 4]);
            float4 b4 = *(const float4*)(&Bs[k][tx * 4]);
            float ar[4] = {a4.x, a4.y, a4.z, a4.w};
            float br[4] = {b4.x, b4.y, b4.z, b4.w};
            #pragma unroll
            for (int i = 0; i < 4; ++i)
                #pragma unroll
                for (int j = 0; j < 4; ++j)
                    acc[i][j] += ar[i] * br[j];
        }
    }

    #pragma unroll
    for (int i = 0; i < 4; ++i) {
        int r = row0 + ty * 4 + i;
        if (r < M) {
            float4 v;
            float* vp = &v.x;
            #pragma unroll
            for (int j = 0; j < 4; ++j) {
                float x = acc[i][j];
                if (bias) x += bias[col0 + tx * 4 + j];
                if (relu_flag) x = fmaxf(x, 0.0f);
                vp[j] = x;
            }
            *(float4*)(C + (size_t)r * N + col0 + tx * 4) = v;
        }
    }
}

// ---------------------------------------------------------------------------
extern "C" void kernel_launch(void* const* d_in, const int* in_sizes, int n_in,
                              void* d_out, int out_size, void* d_ws, size_t ws_size,
                              hipStream_t stream) {
    const float* x  = (const float*)d_in[0];
    const int*   ei = (const int*)d_in[1];
    const float* W1 = (const float*)d_in[2];
    const float* b1 = (const float*)d_in[3];
    const float* W2 = (const float*)d_in[4];
    const float* b2 = (const float*)d_in[5];

    const int n = in_sizes[0] / C_IN;          // 50000
    const int E = in_sizes[1] / 2;             // 800000

    const int* src = ei;
    const int* dst = ei + E;

    // workspace layout
    float* z1   = (float*)d_ws;                          // n*256
    float* h2   = z1 + (size_t)n * C_HID;                // n*128
    float* dinv = h2 + (size_t)n * C_OUT;                // n
    int* counts  = (int*)(dinv + n);                     // n
    int* offsets = counts + n;                           // n+1
    int* cursor  = offsets + (n + 1);                    // n
    int* csr_src = cursor + n;                           // E
    int* block_sums = csr_src + E;                       // <=64
    int* block_base = block_sums + 64;                   // <=64

    float* agg0 = (float*)d_out;   // scratch for Ahat*X (overwritten by final write)
    float* outp = (float*)d_out;

    const int nb = (n + SCHUNK - 1) / SCHUNK;            // 49 (<=64 required)

    // ---- CSR build ----
    hipMemsetAsync(counts, 0, (size_t)n * sizeof(int), stream);
    deg_kernel<<<(E + 255) / 256, 256, 0, stream>>>(dst, counts, E);
    scan_reduce<<<nb, 256, 0, stream>>>(counts, block_sums, n);
    scan_sums<<<1, 64, 0, stream>>>(block_sums, block_base, nb, offsets, n, E);
    scan_apply<<<nb, 256, 0, stream>>>(counts, block_base, offsets, cursor, dinv, n);
    fill_csr<<<(E + 255) / 256, 256, 0, stream>>>(src, dst, cursor, csr_src, E);

    // ---- layer 1: agg0 = Ahat*X ; z1 = relu(agg0@W1 + b1) ----
    agg128_kernel<<<n, 128, 0, stream>>>(x, offsets, csr_src, dinv,
                                         nullptr, agg0, 0, n);
    {
        dim3 grid((n + BM - 1) / BM, C_HID / BN);
        sgemm_bias_relu<<<grid, 256, 0, stream>>>(agg0, W1, b1, z1, n, C_IN, C_HID, 1);
    }

    // ---- layer 2: h2 = z1@W2 ; out = relu(Ahat*h2 + b2) ----
    {
        dim3 grid((n + BM - 1) / BM, C_OUT / BN);
        sgemm_bias_relu<<<grid, 256, 0, stream>>>(z1, W2, nullptr, h2, n, C_HID, C_OUT, 0);
    }
    agg128_kernel<<<n, 128, 0, stream>>>(h2, offsets, csr_src, dinv,
                                         b2, outp, 1, n);
}

// Round 3
// 389.947 us; speedup vs baseline: 1.4124x; 1.1758x over previous
//
#include <hip/hip_runtime.h>

// ---------------------------------------------------------------------------
// GCN 2-layer forward on MI355X.
// out = relu(Ahat * relu((Ahat*X)*W1 + b1) * W2 + b2),  Ahat = D^-1/2 (A+I) D^-1/2
// R1: multi-block scan (scan was 110us on 1 CU).
// R2: agg gather unrolled x8 branchless (was 1 outstanding row-load -> latency
//     bound at 95us, 7% VALUBusy); SGEMM 128x128 tile 8x8/thread (64x64/4x4 was
//     LDS-BW capped at ~1 flop/B ~ 69TF ceiling).
// ---------------------------------------------------------------------------

#define C_IN   128
#define C_HID  256
#define C_OUT  128

// ---------------- degree histogram ----------------
__global__ void deg_kernel(const int* __restrict__ dst, int* __restrict__ counts, int E) {
    int e = blockIdx.x * blockDim.x + threadIdx.x;
    if (e < E) atomicAdd(&counts[dst[e]], 1);
}

// ---------------- multi-block scan: 1024 counts per block ----------------
#define SCHUNK 1024

__global__ __launch_bounds__(256) void scan_reduce(const int* __restrict__ counts,
                                                   int* __restrict__ block_sums, int n) {
    int b = blockIdx.x;
    int base = b * SCHUNK;
    int t = threadIdx.x;
    int s = 0;
    #pragma unroll
    for (int u = 0; u < 4; ++u) {
        int i = base + t * 4 + u;
        if (i < n) s += counts[i];
    }
    #pragma unroll
    for (int off = 32; off; off >>= 1) s += __shfl_down(s, off, 64);
    __shared__ int ws[4];
    int wave = t >> 6;
    if ((t & 63) == 0) ws[wave] = s;
    __syncthreads();
    if (t == 0) block_sums[b] = ws[0] + ws[1] + ws[2] + ws[3];
}

__global__ __launch_bounds__(64) void scan_sums(const int* __restrict__ block_sums,
                                                int* __restrict__ block_base, int nb,
                                                int* __restrict__ offsets, int n, int E) {
    int t = threadIdx.x;
    int v = (t < nb) ? block_sums[t] : 0;
    int x = v;
    #pragma unroll
    for (int off = 1; off < 64; off <<= 1) {
        int y = __shfl_up(x, off, 64);
        if (t >= off) x += y;
    }
    if (t < nb) block_base[t] = x - v;          // exclusive prefix
    if (t == 0) offsets[n] = E;
}

__global__ __launch_bounds__(256) void scan_apply(const int* __restrict__ counts,
                                                  const int* __restrict__ block_base,
                                                  int* __restrict__ offsets,
                                                  int* __restrict__ cursor,
                                                  float* __restrict__ dinv, int n) {
    int b = blockIdx.x;
    int base_i = b * SCHUNK;
    int t = threadIdx.x;
    int c[4];
    #pragma unroll
    for (int u = 0; u < 4; ++u) {
        int i = base_i + t * 4 + u;
        c[u] = (i < n) ? counts[i] : 0;
    }
    int tot = c[0] + c[1] + c[2] + c[3];
    int x = tot;
    int lane = t & 63;
    #pragma unroll
    for (int off = 1; off < 64; off <<= 1) {
        int y = __shfl_up(x, off, 64);
        if (lane >= off) x += y;
    }
    __shared__ int ws[4];
    int wave = t >> 6;
    if (lane == 63) ws[wave] = x;
    __syncthreads();
    int wbase = 0;
    for (int w = 0; w < wave; ++w) wbase += ws[w];
    int run = block_base[b] + wbase + (x - tot);
    #pragma unroll
    for (int u = 0; u < 4; ++u) {
        int i = base_i + t * 4 + u;
        if (i < n) {
            offsets[i] = run;
            cursor[i]  = run;
            dinv[i]    = rsqrtf((float)(c[u] + 1));   // +1 self-loop
            run += c[u];
        }
    }
}

__global__ void fill_csr(const int* __restrict__ src, const int* __restrict__ dst,
                         int* __restrict__ cursor, int* __restrict__ csr_src, int E) {
    int e = blockIdx.x * blockDim.x + threadIdx.x;
    if (e < E) {
        int p = atomicAdd(&cursor[dst[e]], 1);
        csr_src[p] = src[e];
    }
}

// ---------------- pull aggregation, 128-wide, unroll-8 branchless ----------
// out[i][c] = dinv[i] * ( dinv[i]*h[i][c] + sum_{j in N(i)} dinv[j]*h[j][c] )
// csr_src has >= 8 ints of slack past E (block_sums follows it in ws), so the
// unconditional csr_src[kk] reads are safe; OOB lanes get j selected to 0 and
// weight 0.
__global__ __launch_bounds__(128) void agg128_kernel(
        const float* __restrict__ h, const int* __restrict__ offsets,
        const int* __restrict__ csr_src, const float* __restrict__ dinv,
        const float* __restrict__ bias, float* __restrict__ out,
        int relu_flag, int n) {
    int i = blockIdx.x;
    int c = threadIdx.x;            // 0..127
    float di = dinv[i];
    float acc = di * h[(size_t)i * 128 + c];
    int lo = offsets[i], hi = offsets[i + 1];
    for (int k = lo; k < hi; k += 8) {
        int jj[8]; float w[8];
        #pragma unroll
        for (int u = 0; u < 8; ++u) {
            int kk = k + u;
            int j = csr_src[kk];               // unconditional; slack past E
            bool ok = kk < hi;
            j = ok ? j : 0;
            float d = dinv[j];
            jj[u] = j;
            w[u] = ok ? d : 0.0f;
        }
        float part = 0.0f;
        #pragma unroll
        for (int u = 0; u < 8; ++u)
            part += w[u] * h[(size_t)jj[u] * 128 + c];
        acc += part;
    }
    float v = di * acc;
    if (bias) v += bias[c];
    if (relu_flag) v = fmaxf(v, 0.0f);
    out[(size_t)i * 128 + c] = v;
}

// ---------------- fp32 SGEMM 128x128, 8x8/thread, fused bias+relu ----------
// Per-thread 2x2 blocks of 4x4: rows {ty*4+i, 64+ty*4+i}, cols {tx*4+j, 64+tx*4+j}.
#define GBM 128
#define GBN 128
#define GBK 16
__global__ __launch_bounds__(256) void sgemm_bias_relu(
        const float* __restrict__ A, const float* __restrict__ B,
        const float* __restrict__ bias, float* __restrict__ C,
        int M, int K, int N, int relu_flag) {
    __shared__ float As[GBK][GBM + 4];   // [k][m], +4 pad -> 2-way (free) store conflicts
    __shared__ float Bs[GBK][GBN];

    int tid = threadIdx.x;
    int tx = tid & 15;             // 0..15 (N dir)
    int ty = tid >> 4;             // 0..15 (M dir)
    int row0 = blockIdx.x * GBM;
    int col0 = blockIdx.y * GBN;

    // A tile 128x16: per-thread float4 at rows (tid>>2, tid>>2+64), cols (tid&3)*4
    int a_r = tid >> 2;            // 0..63
    int a_c = (tid & 3) * 4;       // 0,4,8,12
    // B tile 16x128: per-thread float4 at row tid>>4, cols (tid&15)*4 (+64)
    int b_r = tid >> 4;            // 0..15
    int b_c = (tid & 15) * 4;      // 0..60

    float acc[2][2][4][4] = {};    // [mi][ni][i][j]

    for (int k0 = 0; k0 < K; k0 += GBK) {
        int ar0 = row0 + a_r, ar1 = ar0 + 64;
        float4 av0 = (ar0 < M) ? *(const float4*)(A + (size_t)ar0 * K + k0 + a_c)
                               : make_float4(0.f, 0.f, 0.f, 0.f);
        float4 av1 = (ar1 < M) ? *(const float4*)(A + (size_t)ar1 * K + k0 + a_c)
                               : make_float4(0.f, 0.f, 0.f, 0.f);
        float4 bv0 = *(const float4*)(B + (size_t)(k0 + b_r) * N + col0 + b_c);
        float4 bv1 = *(const float4*)(B + (size_t)(k0 + b_r) * N + col0 + b_c + 64);
        __syncthreads();
        As[a_c + 0][a_r] = av0.x;  As[a_c + 1][a_r] = av0.y;
        As[a_c + 2][a_r] = av0.z;  As[a_c + 3][a_r] = av0.w;
        As[a_c + 0][a_r + 64] = av1.x;  As[a_c + 1][a_r + 64] = av1.y;
        As[a_c + 2][a_r + 64] = av1.z;  As[a_c + 3][a_r + 64] = av1.w;
        *(float4*)(&Bs[b_r][b_c]) = bv0;
        *(float4*)(&Bs[b_r][b_c + 64]) = bv1;
        __syncthreads();
        #pragma unroll
        for (int k = 0; k < GBK; ++k) {
            float4 a0 = *(const float4*)(&As[k][ty * 4]);
            float4 a1 = *(const float4*)(&As[k][ty * 4 + 64]);
            float4 b0 = *(const float4*)(&Bs[k][tx * 4]);
            float4 b1 = *(const float4*)(&Bs[k][tx * 4 + 64]);
            float am[2][4] = {{a0.x, a0.y, a0.z, a0.w}, {a1.x, a1.y, a1.z, a1.w}};
            float bn[2][4] = {{b0.x, b0.y, b0.z, b0.w}, {b1.x, b1.y, b1.z, b1.w}};
            #pragma unroll
            for (int mi = 0; mi < 2; ++mi)
                #pragma unroll
                for (int ni = 0; ni < 2; ++ni)
                    #pragma unroll
                    for (int i = 0; i < 4; ++i)
                        #pragma unroll
                        for (int j = 0; j < 4; ++j)
                            acc[mi][ni][i][j] += am[mi][i] * bn[ni][j];
        }
    }

    #pragma unroll
    for (int mi = 0; mi < 2; ++mi) {
        #pragma unroll
        for (int i = 0; i < 4; ++i) {
            int r = row0 + mi * 64 + ty * 4 + i;
            if (r < M) {
                #pragma unroll
                for (int ni = 0; ni < 2; ++ni) {
                    int cbase = col0 + ni * 64 + tx * 4;
                    float4 v;
                    float* vp = &v.x;
                    #pragma unroll
                    for (int j = 0; j < 4; ++j) {
                        float x = acc[mi][ni][i][j];
                        if (bias) x += bias[cbase + j];
                        if (relu_flag) x = fmaxf(x, 0.0f);
                        vp[j] = x;
                    }
                    *(float4*)(C + (size_t)r * N + cbase) = v;
                }
            }
        }
    }
}

// ---------------------------------------------------------------------------
extern "C" void kernel_launch(void* const* d_in, const int* in_sizes, int n_in,
                              void* d_out, int out_size, void* d_ws, size_t ws_size,
                              hipStream_t stream) {
    const float* x  = (const float*)d_in[0];
    const int*   ei = (const int*)d_in[1];
    const float* W1 = (const float*)d_in[2];
    const float* b1 = (const float*)d_in[3];
    const float* W2 = (const float*)d_in[4];
    const float* b2 = (const float*)d_in[5];

    const int n = in_sizes[0] / C_IN;          // 50000
    const int E = in_sizes[1] / 2;             // 800000

    const int* src = ei;
    const int* dst = ei + E;

    // workspace layout
    float* z1   = (float*)d_ws;                          // n*256
    float* h2   = z1 + (size_t)n * C_HID;                // n*128
    float* dinv = h2 + (size_t)n * C_OUT;                // n
    int* counts  = (int*)(dinv + n);                     // n
    int* offsets = counts + n;                           // n+1
    int* cursor  = offsets + (n + 1);                    // n
    int* csr_src = cursor + n;                           // E (+slack: block_sums follows)
    int* block_sums = csr_src + E;                       // 64
    int* block_base = block_sums + 64;                   // 64

    float* agg0 = (float*)d_out;   // scratch for Ahat*X (overwritten by final write)
    float* outp = (float*)d_out;

    const int nb = (n + SCHUNK - 1) / SCHUNK;            // 49 (<=64 required)

    // ---- CSR build ----
    hipMemsetAsync(counts, 0, (size_t)n * sizeof(int), stream);
    deg_kernel<<<(E + 255) / 256, 256, 0, stream>>>(dst, counts, E);
    scan_reduce<<<nb, 256, 0, stream>>>(counts, block_sums, n);
    scan_sums<<<1, 64, 0, stream>>>(block_sums, block_base, nb, offsets, n, E);
    scan_apply<<<nb, 256, 0, stream>>>(counts, block_base, offsets, cursor, dinv, n);
    fill_csr<<<(E + 255) / 256, 256, 0, stream>>>(src, dst, cursor, csr_src, E);

    // ---- layer 1: agg0 = Ahat*X ; z1 = relu(agg0@W1 + b1) ----
    agg128_kernel<<<n, 128, 0, stream>>>(x, offsets, csr_src, dinv,
                                         nullptr, agg0, 0, n);
    {
        dim3 grid((n + GBM - 1) / GBM, C_HID / GBN);     // (391, 2)
        sgemm_bias_relu<<<grid, 256, 0, stream>>>(agg0, W1, b1, z1, n, C_IN, C_HID, 1);
    }

    // ---- layer 2: h2 = z1@W2 ; out = relu(Ahat*h2 + b2) ----
    {
        dim3 grid((n + GBM - 1) / GBM, C_OUT / GBN);     // (391, 1)
        sgemm_bias_relu<<<grid, 256, 0, stream>>>(z1, W2, nullptr, h2, n, C_HID, C_OUT, 0);
    }
    agg128_kernel<<<n, 128, 0, stream>>>(h2, offsets, csr_src, dinv,
                                         b2, outp, 1, n);
}

// Round 4
// 355.055 us; speedup vs baseline: 1.5512x; 1.0983x over previous
//
#include <hip/hip_runtime.h>

// ---------------------------------------------------------------------------
// GCN 2-layer forward on MI355X.
// out = relu(Ahat * relu((Ahat*X)*W1 + b1) * W2 + b2),  Ahat = D^-1/2 (A+I) D^-1/2
// R1: multi-block scan. R2: agg unroll-8; 128x128 fp32 GEMM.
// R3: GEMMs moved to bf16-split MFMA (Ootomo 3-mult: AhiBhi+AhiBlo+AloBhi,
//     fp32-accurate to ~2^-18). fp32 path was 48TF, MfmaUtil=0; matrix pipe idle.
//     Operands flow as packed (hi<<16|lo) uint32 — same bytes as fp32, coalesced.
// ---------------------------------------------------------------------------

#define C_IN   128
#define C_HID  256
#define C_OUT  128

typedef __attribute__((ext_vector_type(8))) short short8;
typedef __attribute__((ext_vector_type(4))) float floatx4;

__device__ __forceinline__ unsigned short f2bf(float f) {
    unsigned u = __float_as_uint(f);
    u += 0x7FFFu + ((u >> 16) & 1u);      // RNE
    return (unsigned short)(u >> 16);
}
__device__ __forceinline__ float bf2f(unsigned short b) {
    return __uint_as_float(((unsigned)b) << 16);
}
__device__ __forceinline__ unsigned pack_hilo(float f) {
    unsigned short hi = f2bf(f);
    unsigned short lo = f2bf(f - bf2f(hi));
    return ((unsigned)hi << 16) | (unsigned)lo;
}

// ---------------- degree histogram ----------------
__global__ void deg_kernel(const int* __restrict__ dst, int* __restrict__ counts, int E) {
    int e = blockIdx.x * blockDim.x + threadIdx.x;
    if (e < E) atomicAdd(&counts[dst[e]], 1);
}

// ---------------- multi-block scan: 1024 counts per block ----------------
#define SCHUNK 1024

__global__ __launch_bounds__(256) void scan_reduce(const int* __restrict__ counts,
                                                   int* __restrict__ block_sums, int n) {
    int b = blockIdx.x;
    int base = b * SCHUNK;
    int t = threadIdx.x;
    int s = 0;
    #pragma unroll
    for (int u = 0; u < 4; ++u) {
        int i = base + t * 4 + u;
        if (i < n) s += counts[i];
    }
    #pragma unroll
    for (int off = 32; off; off >>= 1) s += __shfl_down(s, off, 64);
    __shared__ int ws[4];
    int wave = t >> 6;
    if ((t & 63) == 0) ws[wave] = s;
    __syncthreads();
    if (t == 0) block_sums[b] = ws[0] + ws[1] + ws[2] + ws[3];
}

__global__ __launch_bounds__(64) void scan_sums(const int* __restrict__ block_sums,
                                                int* __restrict__ block_base, int nb,
                                                int* __restrict__ offsets, int n, int E) {
    int t = threadIdx.x;
    int v = (t < nb) ? block_sums[t] : 0;
    int x = v;
    #pragma unroll
    for (int off = 1; off < 64; off <<= 1) {
        int y = __shfl_up(x, off, 64);
        if (t >= off) x += y;
    }
    if (t < nb) block_base[t] = x - v;
    if (t == 0) offsets[n] = E;
}

__global__ __launch_bounds__(256) void scan_apply(const int* __restrict__ counts,
                                                  const int* __restrict__ block_base,
                                                  int* __restrict__ offsets,
                                                  int* __restrict__ cursor,
                                                  float* __restrict__ dinv, int n) {
    int b = blockIdx.x;
    int base_i = b * SCHUNK;
    int t = threadIdx.x;
    int c[4];
    #pragma unroll
    for (int u = 0; u < 4; ++u) {
        int i = base_i + t * 4 + u;
        c[u] = (i < n) ? counts[i] : 0;
    }
    int tot = c[0] + c[1] + c[2] + c[3];
    int x = tot;
    int lane = t & 63;
    #pragma unroll
    for (int off = 1; off < 64; off <<= 1) {
        int y = __shfl_up(x, off, 64);
        if (lane >= off) x += y;
    }
    __shared__ int ws[4];
    int wave = t >> 6;
    if (lane == 63) ws[wave] = x;
    __syncthreads();
    int wbase = 0;
    for (int w = 0; w < wave; ++w) wbase += ws[w];
    int run = block_base[b] + wbase + (x - tot);
    #pragma unroll
    for (int u = 0; u < 4; ++u) {
        int i = base_i + t * 4 + u;
        if (i < n) {
            offsets[i] = run;
            cursor[i]  = run;
            dinv[i]    = rsqrtf((float)(c[u] + 1));   // +1 self-loop
            run += c[u];
        }
    }
}

__global__ void fill_csr(const int* __restrict__ src, const int* __restrict__ dst,
                         int* __restrict__ cursor, int* __restrict__ csr_src, int E) {
    int e = blockIdx.x * blockDim.x + threadIdx.x;
    if (e < E) {
        int p = atomicAdd(&cursor[dst[e]], 1);
        csr_src[p] = src[e];
    }
}

// ---------------- weight cast+transpose: W[K][N] f32 -> Wt[N][K] packed ----
__global__ void cast_w_t(const float* __restrict__ W, unsigned* __restrict__ Wtp,
                         int K, int N) {
    int idx = blockIdx.x * blockDim.x + threadIdx.x;
    if (idx < K * N) {
        int k = idx / N, nn = idx - k * N;
        Wtp[(size_t)nn * K + k] = pack_hilo(W[idx]);
    }
}

// ---------------- pull aggregation, 128-wide, unroll-8 branchless ----------
// out[i][c] = dinv[i]*( dinv[i]*h[i][c] + sum_j dinv[j]*h[j][c] ) (+bias)(relu)
// Writes fp32 (out_f) or packed hi|lo (out_p). csr_src has slack past E.
__global__ __launch_bounds__(128) void agg128_kernel(
        const float* __restrict__ h, const int* __restrict__ offsets,
        const int* __restrict__ csr_src, const float* __restrict__ dinv,
        const float* __restrict__ bias, float* __restrict__ out_f,
        unsigned* __restrict__ out_p, int relu_flag, int n) {
    int i = blockIdx.x;
    int c = threadIdx.x;            // 0..127
    float di = dinv[i];
    float acc = di * h[(size_t)i * 128 + c];
    int lo = offsets[i], hi = offsets[i + 1];
    for (int k = lo; k < hi; k += 8) {
        int jj[8]; float w[8];
        #pragma unroll
        for (int u = 0; u < 8; ++u) {
            int kk = k + u;
            int j = csr_src[kk];               // unconditional; slack past E
            bool ok = kk < hi;
            j = ok ? j : 0;
            float d = dinv[j];
            jj[u] = j;
            w[u] = ok ? d : 0.0f;
        }
        float part = 0.0f;
        #pragma unroll
        for (int u = 0; u < 8; ++u)
            part += w[u] * h[(size_t)jj[u] * 128 + c];
        acc += part;
    }
    float v = di * acc;
    if (bias) v += bias[c];
    if (relu_flag) v = fmaxf(v, 0.0f);
    if (out_f) out_f[(size_t)i * 128 + c] = v;
    else       out_p[(size_t)i * 128 + c] = pack_hilo(v);
}

// ---------------- bf16-split MFMA GEMM, 128x128 tile ----------------------
// C = A*B (+bias)(relu). A: [M][K] packed hi|lo. Btp: [N][K] packed (B^T).
// 4 waves; wave computes 64x64 as 4x4 grid of 16x16x32 MFMAs; 3 mults/pair.
// A-frag: A[m=lane&15][k=(lane>>4)*8+j]; C/D: col=lane&15,row=(lane>>4)*4+reg.
#define TM 128
#define TN 128
#define TK 32
#define LDK 40    // halfs per LDS row: 80B stride -> b128 frag reads 2-way (free)

__global__ __launch_bounds__(256) void mfma_gemm(
        const unsigned* __restrict__ Ap, const unsigned* __restrict__ Btp,
        const float* __restrict__ bias, float* __restrict__ Cf,
        unsigned* __restrict__ Cp, int M, int K, int N, int relu_flag) {
    __shared__ unsigned short smem[4 * 128 * LDK];   // 40 KB
    unsigned short* As_hi = smem;
    unsigned short* As_lo = smem + 128 * LDK;
    unsigned short* Bs_hi = smem + 2 * 128 * LDK;
    unsigned short* Bs_lo = smem + 3 * 128 * LDK;

    int tid = threadIdx.x;
    int lane = tid & 63;
    int wv = tid >> 6;
    int m0w = (wv & 1) * 64;
    int n0w = (wv >> 1) * 64;
    int row0 = blockIdx.x * TM;
    int col0 = blockIdx.y * TN;

    int sr  = tid >> 2;            // 0..63 (staging row)
    int skc = (tid & 3) * 8;       // packed-uint offset within 32-k

    floatx4 acc[4][4];
    #pragma unroll
    for (int i = 0; i < 4; ++i)
        #pragma unroll
        for (int j = 0; j < 4; ++j)
            acc[i][j] = (floatx4){0.f, 0.f, 0.f, 0.f};

    for (int k0 = 0; k0 < K; k0 += TK) {
        uint4 av[2][2], bv[2][2];
        #pragma unroll
        for (int p = 0; p < 2; ++p) {
            int r = sr + p * 64;
            int ar = row0 + r;
            if (ar < M) {
                const uint4* pa = (const uint4*)(Ap + (size_t)ar * K + k0 + skc);
                av[p][0] = pa[0];  av[p][1] = pa[1];
            } else {
                av[p][0] = make_uint4(0, 0, 0, 0);
                av[p][1] = make_uint4(0, 0, 0, 0);
            }
            const uint4* pb = (const uint4*)(Btp + (size_t)(col0 + r) * K + k0 + skc);
            bv[p][0] = pb[0];  bv[p][1] = pb[1];
        }
        __syncthreads();          // prev iter frag reads done
        #pragma unroll
        for (int p = 0; p < 2; ++p) {
            int r = sr + p * 64;
            unsigned ua[8] = {av[p][0].x, av[p][0].y, av[p][0].z, av[p][0].w,
                              av[p][1].x, av[p][1].y, av[p][1].z, av[p][1].w};
            unsigned ub[8] = {bv[p][0].x, bv[p][0].y, bv[p][0].z, bv[p][0].w,
                              bv[p][1].x, bv[p][1].y, bv[p][1].z, bv[p][1].w};
            short8 ahs, als, bhs, bls;
            #pragma unroll
            for (int j = 0; j < 8; ++j) {
                ahs[j] = (short)(ua[j] >> 16);  als[j] = (short)(ua[j] & 0xFFFFu);
                bhs[j] = (short)(ub[j] >> 16);  bls[j] = (short)(ub[j] & 0xFFFFu);
            }
            *(short8*)&As_hi[r * LDK + skc] = ahs;
            *(short8*)&As_lo[r * LDK + skc] = als;
            *(short8*)&Bs_hi[r * LDK + skc] = bhs;
            *(short8*)&Bs_lo[r * LDK + skc] = bls;
        }
        __syncthreads();
        short8 ah[4], al[4], bh[4], bl[4];
        int ka = (lane >> 4) * 8;
        #pragma unroll
        for (int mi = 0; mi < 4; ++mi) {
            int rr = m0w + mi * 16 + (lane & 15);
            ah[mi] = *(const short8*)&As_hi[rr * LDK + ka];
            al[mi] = *(const short8*)&As_lo[rr * LDK + ka];
        }
        #pragma unroll
        for (int ni = 0; ni < 4; ++ni) {
            int cc = n0w + ni * 16 + (lane & 15);
            bh[ni] = *(const short8*)&Bs_hi[cc * LDK + ka];
            bl[ni] = *(const short8*)&Bs_lo[cc * LDK + ka];
        }
        #pragma unroll
        for (int mi = 0; mi < 4; ++mi)
            #pragma unroll
            for (int ni = 0; ni < 4; ++ni) {
                acc[mi][ni] = __builtin_amdgcn_mfma_f32_16x16x32_bf16(al[mi], bh[ni], acc[mi][ni], 0, 0, 0);
                acc[mi][ni] = __builtin_amdgcn_mfma_f32_16x16x32_bf16(ah[mi], bl[ni], acc[mi][ni], 0, 0, 0);
                acc[mi][ni] = __builtin_amdgcn_mfma_f32_16x16x32_bf16(ah[mi], bh[ni], acc[mi][ni], 0, 0, 0);
            }
    }

    // epilogue: C/D mapping col=lane&15, row=(lane>>4)*4+reg
    #pragma unroll
    for (int mi = 0; mi < 4; ++mi) {
        #pragma unroll
        for (int reg = 0; reg < 4; ++reg) {
            int r = row0 + m0w + mi * 16 + (lane >> 4) * 4 + reg;
            if (r < M) {
                #pragma unroll
                for (int ni = 0; ni < 4; ++ni) {
                    int c = col0 + n0w + ni * 16 + (lane & 15);
                    float v = acc[mi][ni][reg];
                    if (bias) v += bias[c];
                    if (relu_flag) v = fmaxf(v, 0.0f);
                    if (Cf) Cf[(size_t)r * N + c] = v;
                    else    Cp[(size_t)r * N + c] = pack_hilo(v);
                }
            }
        }
    }
}

// ---------------------------------------------------------------------------
extern "C" void kernel_launch(void* const* d_in, const int* in_sizes, int n_in,
                              void* d_out, int out_size, void* d_ws, size_t ws_size,
                              hipStream_t stream) {
    const float* x  = (const float*)d_in[0];
    const int*   ei = (const int*)d_in[1];
    const float* W1 = (const float*)d_in[2];
    const float* b1 = (const float*)d_in[3];
    const float* W2 = (const float*)d_in[4];
    const float* b2 = (const float*)d_in[5];

    const int n = in_sizes[0] / C_IN;          // 50000
    const int E = in_sizes[1] / 2;             // 800000

    const int* src = ei;
    const int* dst = ei + E;

    // workspace layout (~81 MB)
    float*    h2  = (float*)d_ws;                        // n*128 f32
    unsigned* z1p = (unsigned*)(h2 + (size_t)n * C_OUT); // n*256 packed
    unsigned* w1t = z1p + (size_t)n * C_HID;             // 128*256
    unsigned* w2t = w1t + C_IN * C_HID;                  // 256*128
    float*    dinv = (float*)(w2t + C_HID * C_OUT);      // n
    int* counts  = (int*)(dinv + n);                     // n
    int* offsets = counts + n;                           // n+1
    int* cursor  = offsets + (n + 1);                    // n
    int* csr_src = cursor + n;                           // E (+slack follows)
    int* block_sums = csr_src + E;                       // 64
    int* block_base = block_sums + 64;                   // 64

    unsigned* agg0p = (unsigned*)d_out;    // n*128 packed, overwritten by final out
    float*    outp  = (float*)d_out;

    const int nb = (n + SCHUNK - 1) / SCHUNK;            // 49

    // ---- CSR build ----
    hipMemsetAsync(counts, 0, (size_t)n * sizeof(int), stream);
    deg_kernel<<<(E + 255) / 256, 256, 0, stream>>>(dst, counts, E);
    scan_reduce<<<nb, 256, 0, stream>>>(counts, block_sums, n);
    scan_sums<<<1, 64, 0, stream>>>(block_sums, block_base, nb, offsets, n, E);
    scan_apply<<<nb, 256, 0, stream>>>(counts, block_base, offsets, cursor, dinv, n);
    fill_csr<<<(E + 255) / 256, 256, 0, stream>>>(src, dst, cursor, csr_src, E);

    // ---- weight cast+transpose (tiny) ----
    cast_w_t<<<(C_IN * C_HID + 255) / 256, 256, 0, stream>>>(W1, w1t, C_IN, C_HID);
    cast_w_t<<<(C_HID * C_OUT + 255) / 256, 256, 0, stream>>>(W2, w2t, C_HID, C_OUT);

    // ---- layer 1: agg0 = Ahat*X (packed) ; z1 = relu(agg0@W1 + b1) (packed) ----
    agg128_kernel<<<n, 128, 0, stream>>>(x, offsets, csr_src, dinv,
                                         nullptr, nullptr, agg0p, 0, n);
    {
        dim3 grid((n + TM - 1) / TM, C_HID / TN);        // (391, 2)
        mfma_gemm<<<grid, 256, 0, stream>>>(agg0p, w1t, b1, nullptr, z1p,
                                            n, C_IN, C_HID, 1);
    }

    // ---- layer 2: h2 = z1@W2 (f32) ; out = relu(Ahat*h2 + b2) ----
    {
        dim3 grid((n + TM - 1) / TM, C_OUT / TN);        // (391, 1)
        mfma_gemm<<<grid, 256, 0, stream>>>(z1p, w2t, nullptr, h2, nullptr,
                                            n, C_HID, C_OUT, 0);
    }
    agg128_kernel<<<n, 128, 0, stream>>>(h2, offsets, csr_src, dinv,
                                         b2, outp, nullptr, 1, n);
}

// Round 5
// 352.736 us; speedup vs baseline: 1.5614x; 1.0066x over previous
//
#include <hip/hip_runtime.h>

// ---------------------------------------------------------------------------
// GCN 2-layer forward on MI355X.
// out = relu(Ahat * relu((Ahat*X)*W1 + b1) * W2 + b2),  Ahat = D^-1/2 (A+I) D^-1/2
// R1: multi-block scan. R2: agg unroll-8; 128x128 fp32 GEMM.
// R3: GEMMs -> bf16-split MFMA (Ootomo 3-mult), packed (hi<<16|lo) operand flow.
// R4: agg was BW-bound (47% HBM counted, 410MB useful gather/call). Gather in
//     bf16 (hi-only): halves gather bytes; 1 wave/node, ushort2/lane (256B row
//     transactions). Accum/dinv/outputs stay fp32; GEMM operands stay split.
// ---------------------------------------------------------------------------

#define C_IN   128
#define C_HID  256
#define C_OUT  128

typedef __attribute__((ext_vector_type(8))) short short8;
typedef __attribute__((ext_vector_type(4))) float floatx4;

__device__ __forceinline__ unsigned short f2bf(float f) {
    unsigned u = __float_as_uint(f);
    u += 0x7FFFu + ((u >> 16) & 1u);      // RNE
    return (unsigned short)(u >> 16);
}
__device__ __forceinline__ float bf2f(unsigned short b) {
    return __uint_as_float(((unsigned)b) << 16);
}
__device__ __forceinline__ unsigned pack_hilo(float f) {
    unsigned short hi = f2bf(f);
    unsigned short lo = f2bf(f - bf2f(hi));
    return ((unsigned)hi << 16) | (unsigned)lo;
}

// ---------------- degree histogram ----------------
__global__ void deg_kernel(const int* __restrict__ dst, int* __restrict__ counts, int E) {
    int e = blockIdx.x * blockDim.x + threadIdx.x;
    if (e < E) atomicAdd(&counts[dst[e]], 1);
}

// ---------------- multi-block scan: 1024 counts per block ----------------
#define SCHUNK 1024

__global__ __launch_bounds__(256) void scan_reduce(const int* __restrict__ counts,
                                                   int* __restrict__ block_sums, int n) {
    int b = blockIdx.x;
    int base = b * SCHUNK;
    int t = threadIdx.x;
    int s = 0;
    #pragma unroll
    for (int u = 0; u < 4; ++u) {
        int i = base + t * 4 + u;
        if (i < n) s += counts[i];
    }
    #pragma unroll
    for (int off = 32; off; off >>= 1) s += __shfl_down(s, off, 64);
    __shared__ int ws[4];
    int wave = t >> 6;
    if ((t & 63) == 0) ws[wave] = s;
    __syncthreads();
    if (t == 0) block_sums[b] = ws[0] + ws[1] + ws[2] + ws[3];
}

__global__ __launch_bounds__(64) void scan_sums(const int* __restrict__ block_sums,
                                                int* __restrict__ block_base, int nb,
                                                int* __restrict__ offsets, int n, int E) {
    int t = threadIdx.x;
    int v = (t < nb) ? block_sums[t] : 0;
    int x = v;
    #pragma unroll
    for (int off = 1; off < 64; off <<= 1) {
        int y = __shfl_up(x, off, 64);
        if (t >= off) x += y;
    }
    if (t < nb) block_base[t] = x - v;
    if (t == 0) offsets[n] = E;
}

__global__ __launch_bounds__(256) void scan_apply(const int* __restrict__ counts,
                                                  const int* __restrict__ block_base,
                                                  int* __restrict__ offsets,
                                                  int* __restrict__ cursor,
                                                  float* __restrict__ dinv, int n) {
    int b = blockIdx.x;
    int base_i = b * SCHUNK;
    int t = threadIdx.x;
    int c[4];
    #pragma unroll
    for (int u = 0; u < 4; ++u) {
        int i = base_i + t * 4 + u;
        c[u] = (i < n) ? counts[i] : 0;
    }
    int tot = c[0] + c[1] + c[2] + c[3];
    int x = tot;
    int lane = t & 63;
    #pragma unroll
    for (int off = 1; off < 64; off <<= 1) {
        int y = __shfl_up(x, off, 64);
        if (lane >= off) x += y;
    }
    __shared__ int ws[4];
    int wave = t >> 6;
    if (lane == 63) ws[wave] = x;
    __syncthreads();
    int wbase = 0;
    for (int w = 0; w < wave; ++w) wbase += ws[w];
    int run = block_base[b] + wbase + (x - tot);
    #pragma unroll
    for (int u = 0; u < 4; ++u) {
        int i = base_i + t * 4 + u;
        if (i < n) {
            offsets[i] = run;
            cursor[i]  = run;
            dinv[i]    = rsqrtf((float)(c[u] + 1));   // +1 self-loop
            run += c[u];
        }
    }
}

__global__ void fill_csr(const int* __restrict__ src, const int* __restrict__ dst,
                         int* __restrict__ cursor, int* __restrict__ csr_src, int E) {
    int e = blockIdx.x * blockDim.x + threadIdx.x;
    if (e < E) {
        int p = atomicAdd(&cursor[dst[e]], 1);
        csr_src[p] = src[e];
    }
}

// ---------------- weight cast+transpose: W[K][N] f32 -> Wt[N][K] packed ----
__global__ void cast_w_t(const float* __restrict__ W, unsigned* __restrict__ Wtp,
                         int K, int N) {
    int idx = blockIdx.x * blockDim.x + threadIdx.x;
    if (idx < K * N) {
        int k = idx / N, nn = idx - k * N;
        Wtp[(size_t)nn * K + k] = pack_hilo(W[idx]);
    }
}

// ---------------- x -> bf16 cast, 4 elems/thread ----------------
__global__ void cast_x_bf16(const float* __restrict__ x, unsigned* __restrict__ xb2,
                            int count4) {
    int idx = blockIdx.x * blockDim.x + threadIdx.x;
    if (idx < count4) {
        float4 f = ((const float4*)x)[idx];
        unsigned lo = (unsigned)f2bf(f.x) | ((unsigned)f2bf(f.y) << 16);
        unsigned hi = (unsigned)f2bf(f.z) | ((unsigned)f2bf(f.w) << 16);
        ((uint2*)xb2)[idx] = make_uint2(lo, hi);
    }
}

// ---------------- pull aggregation: bf16 gather, fp32 accumulate ----------
// 1 wave per node, 2 cols/lane (ushort2): each row gather = one 256B wave txn.
// out[i][c] = dinv[i]*( dinv[i]*h[i][c] + sum_j dinv[j]*h[j][c] ) (+bias)(relu)
// csr_src has >=8 ints of slack past E (block_sums follows in ws).
__global__ __launch_bounds__(256) void agg_bf16_kernel(
        const unsigned short* __restrict__ hb, const int* __restrict__ offsets,
        const int* __restrict__ csr_src, const float* __restrict__ dinv,
        const float* __restrict__ bias, float* __restrict__ out_f,
        unsigned* __restrict__ out_p, int relu_flag, int n) {
    int node = blockIdx.x * 4 + (threadIdx.x >> 6);
    if (node >= n) return;
    int lane = threadIdx.x & 63;
    int c0 = lane * 2;
    float di = dinv[node];
    unsigned sv = *(const unsigned*)(hb + (size_t)node * 128 + c0);
    float a0 = di * __uint_as_float((sv & 0xFFFFu) << 16);
    float a1 = di * __uint_as_float(sv & 0xFFFF0000u);
    int lo = offsets[node], hi = offsets[node + 1];
    for (int k = lo; k < hi; k += 8) {
        int jj[8]; float w[8];
        #pragma unroll
        for (int u = 0; u < 8; ++u) {
            int kk = k + u;
            int j = csr_src[kk];               // unconditional; slack past E
            bool ok = kk < hi;
            j = ok ? j : 0;
            jj[u] = j;
            w[u] = ok ? dinv[j] : 0.0f;
        }
        #pragma unroll
        for (int u = 0; u < 8; ++u) {
            unsigned v = *(const unsigned*)(hb + (size_t)jj[u] * 128 + c0);
            a0 += w[u] * __uint_as_float((v & 0xFFFFu) << 16);
            a1 += w[u] * __uint_as_float(v & 0xFFFF0000u);
        }
    }
    float v0 = di * a0, v1 = di * a1;
    if (bias) { v0 += bias[c0]; v1 += bias[c0 + 1]; }
    if (relu_flag) { v0 = fmaxf(v0, 0.0f); v1 = fmaxf(v1, 0.0f); }
    if (out_f) {
        *(float2*)(out_f + (size_t)node * 128 + c0) = make_float2(v0, v1);
    } else {
        *(uint2*)(out_p + (size_t)node * 128 + c0) = make_uint2(pack_hilo(v0), pack_hilo(v1));
    }
}

// ---------------- bf16-split MFMA GEMM, 128x128 tile ----------------------
// C = A*B (+bias)(relu). A: [M][K] packed hi|lo. Btp: [N][K] packed (B^T).
// Output: Cf (f32) | Cp (packed) | Cb (bf16).
#define TM 128
#define TN 128
#define TK 32
#define LDK 40    // halfs per LDS row: 80B stride -> b128 frag reads 2-way (free)

__global__ __launch_bounds__(256) void mfma_gemm(
        const unsigned* __restrict__ Ap, const unsigned* __restrict__ Btp,
        const float* __restrict__ bias, float* __restrict__ Cf,
        unsigned* __restrict__ Cp, unsigned short* __restrict__ Cb,
        int M, int K, int N, int relu_flag) {
    __shared__ unsigned short smem[4 * 128 * LDK];   // 40 KB
    unsigned short* As_hi = smem;
    unsigned short* As_lo = smem + 128 * LDK;
    unsigned short* Bs_hi = smem + 2 * 128 * LDK;
    unsigned short* Bs_lo = smem + 3 * 128 * LDK;

    int tid = threadIdx.x;
    int lane = tid & 63;
    int wv = tid >> 6;
    int m0w = (wv & 1) * 64;
    int n0w = (wv >> 1) * 64;
    int row0 = blockIdx.x * TM;
    int col0 = blockIdx.y * TN;

    int sr  = tid >> 2;            // 0..63 (staging row)
    int skc = (tid & 3) * 8;       // packed-uint offset within 32-k

    floatx4 acc[4][4];
    #pragma unroll
    for (int i = 0; i < 4; ++i)
        #pragma unroll
        for (int j = 0; j < 4; ++j)
            acc[i][j] = (floatx4){0.f, 0.f, 0.f, 0.f};

    for (int k0 = 0; k0 < K; k0 += TK) {
        uint4 av[2][2], bv[2][2];
        #pragma unroll
        for (int p = 0; p < 2; ++p) {
            int r = sr + p * 64;
            int ar = row0 + r;
            if (ar < M) {
                const uint4* pa = (const uint4*)(Ap + (size_t)ar * K + k0 + skc);
                av[p][0] = pa[0];  av[p][1] = pa[1];
            } else {
                av[p][0] = make_uint4(0, 0, 0, 0);
                av[p][1] = make_uint4(0, 0, 0, 0);
            }
            const uint4* pb = (const uint4*)(Btp + (size_t)(col0 + r) * K + k0 + skc);
            bv[p][0] = pb[0];  bv[p][1] = pb[1];
        }
        __syncthreads();          // prev iter frag reads done
        #pragma unroll
        for (int p = 0; p < 2; ++p) {
            int r = sr + p * 64;
            unsigned ua[8] = {av[p][0].x, av[p][0].y, av[p][0].z, av[p][0].w,
                              av[p][1].x, av[p][1].y, av[p][1].z, av[p][1].w};
            unsigned ub[8] = {bv[p][0].x, bv[p][0].y, bv[p][0].z, bv[p][0].w,
                              bv[p][1].x, bv[p][1].y, bv[p][1].z, bv[p][1].w};
            short8 ahs, als, bhs, bls;
            #pragma unroll
            for (int j = 0; j < 8; ++j) {
                ahs[j] = (short)(ua[j] >> 16);  als[j] = (short)(ua[j] & 0xFFFFu);
                bhs[j] = (short)(ub[j] >> 16);  bls[j] = (short)(ub[j] & 0xFFFFu);
            }
            *(short8*)&As_hi[r * LDK + skc] = ahs;
            *(short8*)&As_lo[r * LDK + skc] = als;
            *(short8*)&Bs_hi[r * LDK + skc] = bhs;
            *(short8*)&Bs_lo[r * LDK + skc] = bls;
        }
        __syncthreads();
        short8 ah[4], al[4], bh[4], bl[4];
        int ka = (lane >> 4) * 8;
        #pragma unroll
        for (int mi = 0; mi < 4; ++mi) {
            int rr = m0w + mi * 16 + (lane & 15);
            ah[mi] = *(const short8*)&As_hi[rr * LDK + ka];
            al[mi] = *(const short8*)&As_lo[rr * LDK + ka];
        }
        #pragma unroll
        for (int ni = 0; ni < 4; ++ni) {
            int cc = n0w + ni * 16 + (lane & 15);
            bh[ni] = *(const short8*)&Bs_hi[cc * LDK + ka];
            bl[ni] = *(const short8*)&Bs_lo[cc * LDK + ka];
        }
        #pragma unroll
        for (int mi = 0; mi < 4; ++mi)
            #pragma unroll
            for (int ni = 0; ni < 4; ++ni) {
                acc[mi][ni] = __builtin_amdgcn_mfma_f32_16x16x32_bf16(al[mi], bh[ni], acc[mi][ni], 0, 0, 0);
                acc[mi][ni] = __builtin_amdgcn_mfma_f32_16x16x32_bf16(ah[mi], bl[ni], acc[mi][ni], 0, 0, 0);
                acc[mi][ni] = __builtin_amdgcn_mfma_f32_16x16x32_bf16(ah[mi], bh[ni], acc[mi][ni], 0, 0, 0);
            }
    }

    // epilogue: C/D mapping col=lane&15, row=(lane>>4)*4+reg
    #pragma unroll
    for (int mi = 0; mi < 4; ++mi) {
        #pragma unroll
        for (int reg = 0; reg < 4; ++reg) {
            int r = row0 + m0w + mi * 16 + (lane >> 4) * 4 + reg;
            if (r < M) {
                #pragma unroll
                for (int ni = 0; ni < 4; ++ni) {
                    int c = col0 + n0w + ni * 16 + (lane & 15);
                    float v = acc[mi][ni][reg];
                    if (bias) v += bias[c];
                    if (relu_flag) v = fmaxf(v, 0.0f);
                    if (Cf)      Cf[(size_t)r * N + c] = v;
                    else if (Cp) Cp[(size_t)r * N + c] = pack_hilo(v);
                    else         Cb[(size_t)r * N + c] = f2bf(v);
                }
            }
        }
    }
}

// ---------------------------------------------------------------------------
extern "C" void kernel_launch(void* const* d_in, const int* in_sizes, int n_in,
                              void* d_out, int out_size, void* d_ws, size_t ws_size,
                              hipStream_t stream) {
    const float* x  = (const float*)d_in[0];
    const int*   ei = (const int*)d_in[1];
    const float* W1 = (const float*)d_in[2];
    const float* b1 = (const float*)d_in[3];
    const float* W2 = (const float*)d_in[4];
    const float* b2 = (const float*)d_in[5];

    const int n = in_sizes[0] / C_IN;          // 50000
    const int E = in_sizes[1] / 2;             // 800000

    const int* src = ei;
    const int* dst = ei + E;

    // workspace layout (~81 MB, same total as R3)
    unsigned short* h2b = (unsigned short*)d_ws;         // n*128 bf16
    unsigned* z1p = (unsigned*)(h2b + (size_t)n * C_OUT);// n*256 packed
    unsigned short* xb = (unsigned short*)(z1p + (size_t)n * C_HID); // n*128 bf16
    unsigned* w1t = (unsigned*)(xb + (size_t)n * C_IN);  // 128*256
    unsigned* w2t = w1t + C_IN * C_HID;                  // 256*128
    float*    dinv = (float*)(w2t + C_HID * C_OUT);      // n
    int* counts  = (int*)(dinv + n);                     // n
    int* offsets = counts + n;                           // n+1
    int* cursor  = offsets + (n + 1);                    // n
    int* csr_src = cursor + n;                           // E (+slack follows)
    int* block_sums = csr_src + E;                       // 64
    int* block_base = block_sums + 64;                   // 64

    unsigned* agg0p = (unsigned*)d_out;    // n*128 packed, overwritten by final out
    float*    outp  = (float*)d_out;

    const int nb = (n + SCHUNK - 1) / SCHUNK;            // 49

    // ---- CSR build ----
    hipMemsetAsync(counts, 0, (size_t)n * sizeof(int), stream);
    deg_kernel<<<(E + 255) / 256, 256, 0, stream>>>(dst, counts, E);
    scan_reduce<<<nb, 256, 0, stream>>>(counts, block_sums, n);
    scan_sums<<<1, 64, 0, stream>>>(block_sums, block_base, nb, offsets, n, E);
    scan_apply<<<nb, 256, 0, stream>>>(counts, block_base, offsets, cursor, dinv, n);
    fill_csr<<<(E + 255) / 256, 256, 0, stream>>>(src, dst, cursor, csr_src, E);

    // ---- casts (tiny) ----
    cast_w_t<<<(C_IN * C_HID + 255) / 256, 256, 0, stream>>>(W1, w1t, C_IN, C_HID);
    cast_w_t<<<(C_HID * C_OUT + 255) / 256, 256, 0, stream>>>(W2, w2t, C_HID, C_OUT);
    {
        int count4 = n * C_IN / 4;
        cast_x_bf16<<<(count4 + 255) / 256, 256, 0, stream>>>(x, (unsigned*)xb, count4);
    }

    // ---- layer 1: agg0 = Ahat*X (packed) ; z1 = relu(agg0@W1 + b1) (packed) ----
    agg_bf16_kernel<<<(n + 3) / 4, 256, 0, stream>>>(xb, offsets, csr_src, dinv,
                                                     nullptr, nullptr, agg0p, 0, n);
    {
        dim3 grid((n + TM - 1) / TM, C_HID / TN);        // (391, 2)
        mfma_gemm<<<grid, 256, 0, stream>>>(agg0p, w1t, b1, nullptr, z1p, nullptr,
                                            n, C_IN, C_HID, 1);
    }

    // ---- layer 2: h2 = z1@W2 (bf16) ; out = relu(Ahat*h2 + b2) ----
    {
        dim3 grid((n + TM - 1) / TM, C_OUT / TN);        // (391, 1)
        mfma_gemm<<<grid, 256, 0, stream>>>(z1p, w2t, nullptr, nullptr, nullptr, h2b,
                                            n, C_HID, C_OUT, 0);
    }
    agg_bf16_kernel<<<(n + 3) / 4, 256, 0, stream>>>(h2b, offsets, csr_src, dinv,
                                                     b2, outp, nullptr, 1, n);
}